// Round 1
// baseline (2511.776 us; speedup 1.0000x reference)
//
#include <hip/hip_runtime.h>
#include <stdint.h>

// Lovasz-softmax loss, B=4 C=19 H=W=512.
// Histogram-based counting-sort formulation: exact up to intra-bucket error
// spread <= 2^-10 relative (threshold is ~2% of |loss|~0.95).

#define IGNORE_LBL 255
constexpr int C_CLS = 19;
constexpr int SHIFT = 13;                               // keep 10 mantissa bits
constexpr int NBINS = (0x3F800000 >> SHIFT) + 1;        // 130049 (e in [0,1])
constexpr int HW_C = 512 * 512;                         // per-batch pixel count
constexpr int SCAN_NT = 1024;

__global__ void lovasz_hist_kernel(const float* __restrict__ logits,
                                   const int* __restrict__ gt,
                                   unsigned long long* __restrict__ hist_nf,
                                   float* __restrict__ hist_s,
                                   int P) {
    int p = blockIdx.x * blockDim.x + threadIdx.x;
    if (p >= P) return;
    int b = p >> 18;              // p / HW_C
    int hw = p & (HW_C - 1);
    const float* base = logits + (size_t)b * C_CLS * HW_C + hw;

    float v[C_CLS];
    float mx = -3.4e38f;
#pragma unroll
    for (int c = 0; c < C_CLS; ++c) {
        v[c] = base[(size_t)c * HW_C];
        mx = fmaxf(mx, v[c]);
    }
    float s = 0.f;
#pragma unroll
    for (int c = 0; c < C_CLS; ++c) {
        v[c] = __expf(v[c] - mx);
        s += v[c];
    }
    float inv = 1.0f / s;

    int lbl = gt[p];
    if (lbl == IGNORE_LBL) return;   // invalid pixels contribute nothing

#pragma unroll
    for (int c = 0; c < C_CLS; ++c) {
        float prob = v[c] * inv;
        bool fg = (c == lbl);
        float err = fg ? (1.0f - prob) : prob;          // in [0,1]
        unsigned key = __float_as_uint(err) >> SHIFT;   // monotone for e>=0
        size_t idx = (size_t)c * NBINS + key;
        atomicAdd(&hist_nf[idx], 1ull | ((unsigned long long)(fg ? 1u : 0u) << 32));
        atomicAdd(&hist_s[idx], err);
    }
}

// One block per class: totals, then descending-order chunked prefix scan.
__global__ __launch_bounds__(SCAN_NT)
void lovasz_scan_kernel(const unsigned long long* __restrict__ hist_nf,
                        const float* __restrict__ hist_s,
                        float* __restrict__ class_loss,
                        int* __restrict__ class_present) {
    const int c = blockIdx.x;
    const unsigned long long* nf = hist_nf + (size_t)c * NBINS;
    const float* sums = hist_s + (size_t)c * NBINS;
    const int tid = threadIdx.x;
    const int lane = tid & 63;
    const int wave = tid >> 6;                 // 16 waves

    __shared__ unsigned long long wsum[16];
    __shared__ unsigned long long sh_bcast;

    // ---- Phase 1: total (N | G<<32) for this class ----
    unsigned long long t = 0;
    for (int i = tid; i < NBINS; i += SCAN_NT) t += nf[i];
#pragma unroll
    for (int o = 32; o > 0; o >>= 1) t += __shfl_down(t, o, 64);
    if (lane == 0) wsum[wave] = t;
    __syncthreads();
    if (tid == 0) {
        unsigned long long tot = 0;
        for (int w = 0; w < 16; ++w) tot += wsum[w];
        sh_bcast = tot;
    }
    __syncthreads();
    const long long G = (long long)(sh_bcast >> 32);   // foreground count

    // ---- Phase 2: descending scan over bins, accumulate loss ----
    double lsum = 0.0;
    unsigned long long carry = 0;              // (k | F<<32) from higher keys
    const int nChunks = (NBINS + SCAN_NT - 1) / SCAN_NT;
    for (int ch = 0; ch < nChunks; ++ch) {
        int r = ch * SCAN_NT + tid;            // reverse rank (0 = highest key)
        int bin = NBINS - 1 - r;
        unsigned long long mynf = (bin >= 0) ? nf[bin] : 0ull;
        float mys = (bin >= 0) ? sums[bin] : 0.f;

        // wave-level inclusive scan (packed u64: fields can't cross-carry)
        unsigned long long incl = mynf;
#pragma unroll
        for (int o = 1; o < 64; o <<= 1) {
            unsigned long long u = __shfl_up(incl, o, 64);
            if (lane >= o) incl += u;
        }
        if (lane == 63) wsum[wave] = incl;
        __syncthreads();
        if (tid == 0) {
            unsigned long long run = 0;
            for (int w = 0; w < 16; ++w) { unsigned long long x = wsum[w]; wsum[w] = run; run += x; }
            sh_bcast = run;                    // chunk total
        }
        __syncthreads();

        unsigned long long excl = carry + wsum[wave] + (incl - mynf);
        int n_b = (int)(mynf & 0xffffffffull);
        if (n_b > 0 && G > 0) {
            int f_b = (int)(mynf >> 32);
            long long k0 = (long long)(excl & 0xffffffffull);
            long long F0 = (long long)(excl >> 32);
            long long I0 = G - F0;
            long long U0 = G + k0 - F0;        // >= G > 0
            long long k1 = k0 + n_b;
            long long F1 = F0 + f_b;
            long long I1 = G - F1;
            long long U1 = G + k1 - F1;
            // dJ = J(k1,F1) - J(k0,F0) = I0/U0 - I1/U1, exact int64 numerator
            double dJ = (double)(I0 * U1 - I1 * U0) / ((double)U0 * (double)U1);
            lsum += ((double)mys / (double)n_b) * dJ;
        }
        carry += sh_bcast;
        // no extra barrier needed: next writes to wsum/sh_bcast are ordered
        // behind the next iteration's __syncthreads()
    }

    // ---- reduce lsum over block ----
    __shared__ double dred[16];
#pragma unroll
    for (int o = 32; o > 0; o >>= 1) lsum += __shfl_down(lsum, o, 64);
    if (lane == 0) dred[wave] = lsum;
    __syncthreads();
    if (tid == 0) {
        double tot = 0.0;
        for (int w = 0; w < 16; ++w) tot += dred[w];
        class_loss[c] = (float)tot;
        class_present[c] = (G > 0) ? 1 : 0;
    }
}

__global__ void lovasz_final_kernel(const float* __restrict__ class_loss,
                                    const int* __restrict__ class_present,
                                    float* __restrict__ out) {
    int t = threadIdx.x;
    float l = 0.f; int pr = 0;
    if (t < C_CLS) { pr = class_present[t]; l = pr ? class_loss[t] : 0.f; }
#pragma unroll
    for (int o = 32; o > 0; o >>= 1) {
        l += __shfl_down(l, o, 64);
        pr += __shfl_down(pr, o, 64);
    }
    if (t == 0) out[0] = l / fmaxf((float)pr, 1.0f);
}

extern "C" void kernel_launch(void* const* d_in, const int* in_sizes, int n_in,
                              void* d_out, int out_size, void* d_ws, size_t ws_size,
                              hipStream_t stream) {
    const float* logits = (const float*)d_in[0];
    const int* gt = (const int*)d_in[1];
    float* out = (float*)d_out;
    const int P = in_sizes[1];                 // 1,048,576

    // workspace layout
    size_t nfBytes = (size_t)C_CLS * NBINS * sizeof(unsigned long long);
    size_t nfPad = (nfBytes + 255) & ~(size_t)255;
    size_t sBytes = (size_t)C_CLS * NBINS * sizeof(float);
    size_t sPad = (sBytes + 255) & ~(size_t)255;
    unsigned long long* hist_nf = (unsigned long long*)d_ws;
    float* hist_s = (float*)((char*)d_ws + nfPad);
    float* class_loss = (float*)((char*)d_ws + nfPad + sPad);
    int* class_present = (int*)((char*)d_ws + nfPad + sPad + 256);

    hipMemsetAsync(d_ws, 0, nfPad + sPad, stream);

    int threads = 256;
    lovasz_hist_kernel<<<(P + threads - 1) / threads, threads, 0, stream>>>(
        logits, gt, hist_nf, hist_s, P);
    lovasz_scan_kernel<<<C_CLS, SCAN_NT, 0, stream>>>(
        hist_nf, hist_s, class_loss, class_present);
    lovasz_final_kernel<<<1, 64, 0, stream>>>(class_loss, class_present, out);
}

// Round 2
// 223.150 us; speedup vs baseline: 11.2560x; 11.2560x over previous
//
#include <hip/hip_runtime.h>
#include <stdint.h>

// Lovasz-softmax loss, B=4 C=19 H=W=512, P=1M pixels.
// R2: LDS-privatized geometric histogram (512 bins/class, bucket width <= 2^-8
// => worst-case loss error <= 2^-8 = 0.0039 << 0.019 threshold, since the
// Jaccard curve is monotone and grads >= 0). No global atomics at all.

#define IGNORE_LBL 255
constexpr int C_CLS = 19;
constexpr int NB = 512;                 // bins per class
constexpr int NBT = C_CLS * NB;         // 9728
constexpr int HW_C = 512 * 512;         // per-batch pixel count
constexpr int HIST_GRID = 256;
constexpr int HIST_NT = 1024;
constexpr int SCAN_NT = 1024;

// Geometric binning of e in [0,1]:
//   bin 0          : e < 2^-8           (width 2^-8)
//   exp E=119..126 : 2^(E-118) buckets  (width 2^-9 each)
//   bin 511        : e == 1.0
// Monotone in e; max bucket width 2^-8.
__device__ __forceinline__ int err_bin(float e) {
    unsigned u = __float_as_uint(e);
    if (u >= 0x3F800000u) return NB - 1;
    if (u < 0x3B800000u) return 0;
    int m = (int)(u >> 23) - 118;                       // 1..8
    return (1 << m) - 1 + (int)((u & 0x7FFFFFu) >> (23 - m));
}

__global__ __launch_bounds__(HIST_NT)
void lovasz_hist_kernel(const float* __restrict__ logits,
                        const int* __restrict__ gt,
                        unsigned* __restrict__ cnt_part,
                        float* __restrict__ sum_part,
                        int P) {
    __shared__ unsigned l_cnt[NBT];     // count in [15:0], fg in [31:16]
    __shared__ float l_sum[NBT];
    for (int i = threadIdx.x; i < NBT; i += HIST_NT) { l_cnt[i] = 0u; l_sum[i] = 0.f; }
    __syncthreads();

    const int stride = gridDim.x * blockDim.x;
    for (int p = blockIdx.x * blockDim.x + threadIdx.x; p < P; p += stride) {
        int lbl = gt[p];
        if (lbl == IGNORE_LBL) continue;
        int b = p >> 18;                // p / HW_C
        int hw = p & (HW_C - 1);
        const float* base = logits + (size_t)b * C_CLS * HW_C + hw;

        float v[C_CLS];
        float mx = -3.4e38f;
#pragma unroll
        for (int c = 0; c < C_CLS; ++c) {
            v[c] = base[(size_t)c * HW_C];
            mx = fmaxf(mx, v[c]);
        }
        float s = 0.f;
#pragma unroll
        for (int c = 0; c < C_CLS; ++c) {
            v[c] = __expf(v[c] - mx);
            s += v[c];
        }
        float inv = 1.0f / s;

#pragma unroll
        for (int c = 0; c < C_CLS; ++c) {
            float prob = v[c] * inv;
            bool fg = (c == lbl);
            float e = fg ? (1.0f - prob) : prob;
            e = fminf(fmaxf(e, 0.0f), 1.0f);
            int bin = c * NB + err_bin(e);
            atomicAdd(&l_cnt[bin], fg ? 0x10001u : 1u);
            atomicAdd(&l_sum[bin], e);
        }
    }
    __syncthreads();

    // plain-store partial histogram (counts <= 4096 per field: no overflow)
    unsigned base_out = blockIdx.x * NBT;
    for (int i = threadIdx.x; i < NBT; i += HIST_NT) {
        cnt_part[base_out + i] = l_cnt[i];
        sum_part[base_out + i] = l_sum[i];
    }
}

// One block per class: reduce partials, then single-chunk descending scan.
__global__ __launch_bounds__(SCAN_NT)
void lovasz_scan_kernel(const unsigned* __restrict__ cnt_part,
                        const float* __restrict__ sum_part,
                        float* __restrict__ class_loss,
                        int* __restrict__ class_present) {
    const int c = blockIdx.x;
    const int t = threadIdx.x;
    const int lane = t & 63;
    const int wave = t >> 6;            // 16 waves
    const int bin = t & (NB - 1);
    const int half = t >> 9;            // 0 or 1

    __shared__ unsigned s_n[2][NB];
    __shared__ unsigned s_f[2][NB];
    __shared__ float s_s[2][NB];
    __shared__ unsigned long long wtot[16];
    __shared__ unsigned long long sh_total;

    // ---- Phase 0: reduce 256 partials (split across the two halves) ----
    unsigned n = 0, f = 0; float sm = 0.f;
    const int p0 = half * (HIST_GRID / 2);
    const int p1 = p0 + HIST_GRID / 2;
    const size_t boff = (size_t)c * NB + bin;
    for (int p = p0; p < p1; ++p) {
        unsigned x = cnt_part[(size_t)p * NBT + boff];
        n += x & 0xFFFFu;
        f += x >> 16;
        sm += sum_part[(size_t)p * NBT + boff];
    }
    s_n[half][bin] = n; s_f[half][bin] = f; s_s[half][bin] = sm;
    __syncthreads();

    // ---- Phase 1: single-chunk descending scan (threads 0..511 active) ----
    unsigned long long nf = 0;
    float mys = 0.f;
    if (t < NB) {
        int db = NB - 1 - t;            // descending bin order
        unsigned nn = s_n[0][db] + s_n[1][db];
        unsigned ff = s_f[0][db] + s_f[1][db];
        mys = s_s[0][db] + s_s[1][db];
        nf = (unsigned long long)nn | ((unsigned long long)ff << 32);
    }
    unsigned long long incl = nf;
#pragma unroll
    for (int o = 1; o < 64; o <<= 1) {
        unsigned long long u = __shfl_up(incl, o, 64);
        if (lane >= o) incl += u;
    }
    if (lane == 63) wtot[wave] = incl;  // waves >=8 write zeros (harmless)
    __syncthreads();
    if (t == 0) {
        unsigned long long run = 0;
        for (int w = 0; w < 16; ++w) { unsigned long long x = wtot[w]; wtot[w] = run; run += x; }
        sh_total = run;
    }
    __syncthreads();

    const unsigned long long total = sh_total;
    const long long G = (long long)(total >> 32);
    const unsigned long long excl = wtot[wave] + (incl - nf);

    double lsum = 0.0;
    {
        long long n_b = (long long)(nf & 0xffffffffull);
        if (t < NB && n_b > 0 && G > 0) {
            long long f_b = (long long)(nf >> 32);
            long long k0 = (long long)(excl & 0xffffffffull);
            long long F0 = (long long)(excl >> 32);
            long long I0 = G - F0;
            long long U0 = G + k0 - F0;
            long long F1 = F0 + f_b;
            long long I1 = G - F1;
            long long U1 = G + (k0 + n_b) - F1;
            // dJ = I0/U0 - I1/U1 exactly (int64 cross product, <= 2^41)
            double dJ = (double)(I0 * U1 - I1 * U0) / ((double)U0 * (double)U1);
            lsum = ((double)mys / (double)n_b) * dJ;
        }
    }

    // ---- block reduce (double) ----
    __shared__ double dred[16];
#pragma unroll
    for (int o = 32; o > 0; o >>= 1) lsum += __shfl_down(lsum, o, 64);
    if (lane == 0) dred[wave] = lsum;
    __syncthreads();
    if (t == 0) {
        double tot = 0.0;
        for (int w = 0; w < 16; ++w) tot += dred[w];
        class_loss[c] = (float)tot;
        class_present[c] = (G > 0) ? 1 : 0;
    }
}

__global__ void lovasz_final_kernel(const float* __restrict__ class_loss,
                                    const int* __restrict__ class_present,
                                    float* __restrict__ out) {
    int t = threadIdx.x;
    float l = 0.f; int pr = 0;
    if (t < C_CLS) { pr = class_present[t]; l = pr ? class_loss[t] : 0.f; }
#pragma unroll
    for (int o = 32; o > 0; o >>= 1) {
        l += __shfl_down(l, o, 64);
        pr += __shfl_down(pr, o, 64);
    }
    if (t == 0) out[0] = l / fmaxf((float)pr, 1.0f);
}

extern "C" void kernel_launch(void* const* d_in, const int* in_sizes, int n_in,
                              void* d_out, int out_size, void* d_ws, size_t ws_size,
                              hipStream_t stream) {
    const float* logits = (const float*)d_in[0];
    const int* gt = (const int*)d_in[1];
    float* out = (float*)d_out;
    const int P = in_sizes[1];          // 1,048,576

    // workspace layout (all fully overwritten each call; no memset needed)
    size_t cntBytes = (size_t)HIST_GRID * NBT * sizeof(unsigned);   // ~10 MB
    size_t cntPad = (cntBytes + 255) & ~(size_t)255;
    size_t sumBytes = (size_t)HIST_GRID * NBT * sizeof(float);      // ~10 MB
    size_t sumPad = (sumBytes + 255) & ~(size_t)255;
    unsigned* cnt_part = (unsigned*)d_ws;
    float* sum_part = (float*)((char*)d_ws + cntPad);
    float* class_loss = (float*)((char*)d_ws + cntPad + sumPad);
    int* class_present = (int*)((char*)d_ws + cntPad + sumPad + 256);

    lovasz_hist_kernel<<<HIST_GRID, HIST_NT, 0, stream>>>(
        logits, gt, cnt_part, sum_part, P);
    lovasz_scan_kernel<<<C_CLS, SCAN_NT, 0, stream>>>(
        cnt_part, sum_part, class_loss, class_present);
    lovasz_final_kernel<<<1, 64, 0, stream>>>(class_loss, class_present, out);
}

// Round 3
// 130.448 us; speedup vs baseline: 19.2550x; 1.7106x over previous
//
#include <hip/hip_runtime.h>
#include <stdint.h>

// Lovasz-softmax loss, B=4 C=19 H=W=512, P=1M pixels.
// R3: single native ds_add_u64 per class per pixel (fixed-point esum|cnt|fg),
// 256 geometric bins/class (width <= 2^-7 => loss error bound 0.0078 < 0.019
// threshold; Jaccard curve monotone, grads >= 0), 2 blocks/CU occupancy,
// parallel partial-reduction kernel before the 19-block scan.

#define IGNORE_LBL 255
typedef unsigned long long u64;
constexpr int C_CLS = 19;
constexpr int NB = 256;                 // bins per class
constexpr int NBT = C_CLS * NB;         // 4864
constexpr int HW_C = 512 * 512;         // per-batch pixel count
constexpr int HIST_GRID = 512;
constexpr int HIST_NT = 1024;
constexpr int RED_Q = 8;                // reduction segments (512/8 = 64 each)
constexpr float ESCALE = 262144.f;      // 2^18 fixed-point scale

// Geometric binning of e in [0,1]:
//   bin 0       : e < 2^-7
//   E=120..126  : 2^(E-119) buckets each (width 2^-8)
//   bin 255     : e >= 1.0
// Monotone in e; max bucket width 2^-7 (bin 0 only).
__device__ __forceinline__ int err_bin(float e) {
    unsigned u = __float_as_uint(e);
    if (u >= 0x3F800000u) return NB - 1;
    if (u < 0x3C000000u) return 0;
    int m = (int)(u >> 23) - 119;                       // 1..7
    return (1 << m) - 1 + (int)((u & 0x7FFFFFu) >> (23 - m));
}

__global__ __launch_bounds__(HIST_NT)
void lovasz_hist_kernel(const float* __restrict__ logits,
                        const int* __restrict__ gt,
                        u64* __restrict__ part,
                        int P) {
    __shared__ u64 h[NBT];              // esum[0:31] | cnt[32:45] | fg[46:59]
    for (int i = threadIdx.x; i < NBT; i += HIST_NT) h[i] = 0ull;
    __syncthreads();

    const int stride = gridDim.x * blockDim.x;
    for (int p = blockIdx.x * blockDim.x + threadIdx.x; p < P; p += stride) {
        int lbl = gt[p];
        if (lbl == IGNORE_LBL) continue;
        int b = p >> 18;                // p / HW_C
        int hw = p & (HW_C - 1);
        const float* base = logits + (size_t)b * C_CLS * HW_C + hw;

        float v[C_CLS];
        float mx = -3.4e38f;
#pragma unroll
        for (int c = 0; c < C_CLS; ++c) {
            v[c] = base[(size_t)c * HW_C];
            mx = fmaxf(mx, v[c]);
        }
        float s = 0.f;
#pragma unroll
        for (int c = 0; c < C_CLS; ++c) {
            v[c] = __expf(v[c] - mx);
            s += v[c];
        }
        float inv = 1.0f / s;

#pragma unroll
        for (int c = 0; c < C_CLS; ++c) {
            float prob = v[c] * inv;
            bool fg = (c == lbl);
            float e = fg ? (1.0f - prob) : prob;
            e = fmaxf(e, 0.0f);
            unsigned eq = __float2uint_rn(e * ESCALE);   // <= 2^18
            int bin = c * NB + err_bin(e);
            u64 add = (u64)eq | (1ull << 32) | (fg ? (1ull << 46) : 0ull);
            atomicAdd(&h[bin], add);    // native ds_add_u64
        }
    }
    __syncthreads();

    const size_t base_out = (size_t)blockIdx.x * NBT;
    for (int i = threadIdx.x; i < NBT; i += HIST_NT) part[base_out + i] = h[i];
}

// Fold 512 partials -> RED_Q per bin. grid = RED_Q * 19 blocks of 256 thr.
__global__ __launch_bounds__(256)
void lovasz_reduce_kernel(const u64* __restrict__ part,
                          u64* __restrict__ red_es,
                          u64* __restrict__ red_cf) {
    const int q = blockIdx.x / C_CLS;            // 0..RED_Q-1
    const int seg = blockIdx.x % C_CLS;
    const int bin = seg * NB + threadIdx.x;      // 0..NBT-1
    const int p0 = q * (HIST_GRID / RED_Q);
    u64 es = 0; unsigned cn = 0, fgc = 0;
#pragma unroll 4
    for (int p = p0; p < p0 + HIST_GRID / RED_Q; ++p) {
        u64 x = part[(size_t)p * NBT + bin];
        es += x & 0xFFFFFFFFull;
        cn += (unsigned)((x >> 32) & 0x3FFFu);
        fgc += (unsigned)(x >> 46);
    }
    red_es[(size_t)q * NBT + bin] = es;
    red_cf[(size_t)q * NBT + bin] = (u64)cn | ((u64)fgc << 32);
}

// One block per class: fold RED_Q, then single-chunk descending scan.
__global__ __launch_bounds__(NB)
void lovasz_scan_kernel(const u64* __restrict__ red_es,
                        const u64* __restrict__ red_cf,
                        float* __restrict__ class_loss,
                        int* __restrict__ class_present) {
    const int c = blockIdx.x;
    const int t = threadIdx.x;                   // 0..255
    const int lane = t & 63;
    const int wave = t >> 6;                     // 4 waves

    __shared__ u64 wtot[4];
    __shared__ u64 sh_total;

    // ---- Phase 0: fold the RED_Q reduced partials (descending bin order) ----
    const int db = NB - 1 - t;
    const size_t bo = (size_t)c * NB + db;
    u64 es = 0, nf = 0;                          // nf = cnt | fg<<32
#pragma unroll
    for (int q = 0; q < RED_Q; ++q) {
        es += red_es[(size_t)q * NBT + bo];
        nf += red_cf[(size_t)q * NBT + bo];
    }
    const double mys = (double)es * (1.0 / (double)ESCALE);

    // ---- Phase 1: inclusive scan over the 256 descending bins ----
    u64 incl = nf;
#pragma unroll
    for (int o = 1; o < 64; o <<= 1) {
        u64 u = __shfl_up(incl, o, 64);
        if (lane >= o) incl += u;
    }
    if (lane == 63) wtot[wave] = incl;
    __syncthreads();
    if (t == 0) {
        u64 run = 0;
#pragma unroll
        for (int w = 0; w < 4; ++w) { u64 x = wtot[w]; wtot[w] = run; run += x; }
        sh_total = run;
    }
    __syncthreads();

    const long long G = (long long)(sh_total >> 32);
    const u64 excl = wtot[wave] + (incl - nf);

    double lsum = 0.0;
    {
        long long n_b = (long long)(nf & 0xffffffffull);
        if (n_b > 0 && G > 0) {
            long long f_b = (long long)(nf >> 32);
            long long k0 = (long long)(excl & 0xffffffffull);
            long long F0 = (long long)(excl >> 32);
            long long I0 = G - F0;
            long long U0 = G + k0 - F0;
            long long F1 = F0 + f_b;
            long long I1 = G - F1;
            long long U1 = G + (k0 + n_b) - F1;
            // dJ = I0/U0 - I1/U1 exactly (int64 cross product, <= 2^41)
            double dJ = (double)(I0 * U1 - I1 * U0) / ((double)U0 * (double)U1);
            lsum = (mys / (double)n_b) * dJ;
        }
    }

    // ---- block reduce (double, 4 waves) ----
    __shared__ double dred[4];
#pragma unroll
    for (int o = 32; o > 0; o >>= 1) lsum += __shfl_down(lsum, o, 64);
    if (lane == 0) dred[wave] = lsum;
    __syncthreads();
    if (t == 0) {
        double tot = dred[0] + dred[1] + dred[2] + dred[3];
        class_loss[c] = (float)tot;
        class_present[c] = (G > 0) ? 1 : 0;
    }
}

__global__ void lovasz_final_kernel(const float* __restrict__ class_loss,
                                    const int* __restrict__ class_present,
                                    float* __restrict__ out) {
    int t = threadIdx.x;
    float l = 0.f; int pr = 0;
    if (t < C_CLS) { pr = class_present[t]; l = pr ? class_loss[t] : 0.f; }
#pragma unroll
    for (int o = 32; o > 0; o >>= 1) {
        l += __shfl_down(l, o, 64);
        pr += __shfl_down(pr, o, 64);
    }
    if (t == 0) out[0] = l / fmaxf((float)pr, 1.0f);
}

extern "C" void kernel_launch(void* const* d_in, const int* in_sizes, int n_in,
                              void* d_out, int out_size, void* d_ws, size_t ws_size,
                              hipStream_t stream) {
    const float* logits = (const float*)d_in[0];
    const int* gt = (const int*)d_in[1];
    float* out = (float*)d_out;
    const int P = in_sizes[1];          // 1,048,576

    // workspace layout (all fully overwritten each call; no memset needed)
    size_t partBytes = (size_t)HIST_GRID * NBT * sizeof(u64);       // 19.9 MB
    size_t partPad = (partBytes + 255) & ~(size_t)255;
    size_t redBytes = (size_t)RED_Q * NBT * sizeof(u64);            // 311 KB
    size_t redPad = (redBytes + 255) & ~(size_t)255;
    u64* part = (u64*)d_ws;
    u64* red_es = (u64*)((char*)d_ws + partPad);
    u64* red_cf = (u64*)((char*)d_ws + partPad + redPad);
    float* class_loss = (float*)((char*)d_ws + partPad + 2 * redPad);
    int* class_present = (int*)((char*)d_ws + partPad + 2 * redPad + 256);

    lovasz_hist_kernel<<<HIST_GRID, HIST_NT, 0, stream>>>(logits, gt, part, P);
    lovasz_reduce_kernel<<<RED_Q * C_CLS, 256, 0, stream>>>(part, red_es, red_cf);
    lovasz_scan_kernel<<<C_CLS, NB, 0, stream>>>(red_es, red_cf, class_loss, class_present);
    lovasz_final_kernel<<<1, 64, 0, stream>>>(class_loss, class_present, out);
}

// Round 4
// 129.911 us; speedup vs baseline: 19.3345x; 1.0041x over previous
//
#include <hip/hip_runtime.h>
#include <stdint.h>

// Lovasz-softmax loss, B=4 C=19 H=W=512, P=1M pixels.
// R4: 2 px/thread float2-vectorized hist (2x ILP, half the load insts),
// native ds_add_u64 LDS histogram (256 geometric bins/class, bucket width
// <= 2^-7 => loss error bound 0.0078 < 0.019 threshold), spread reduce,
// scan fused with final via device-scope last-block pattern. 3 dispatches.

#define IGNORE_LBL 255
typedef unsigned long long u64;
constexpr int C_CLS = 19;
constexpr int NB = 256;                 // bins per class
constexpr int NBT = C_CLS * NB;         // 4864
constexpr int HW_C = 512 * 512;         // per-batch pixel count
constexpr int HIST_GRID = 512;
constexpr int HIST_NT = 1024;
constexpr int RED_Q = 8;                // reduction segments (512/8 = 64 each)
constexpr float ESCALE = 262144.f;      // 2^18 fixed-point scale

// Geometric binning of e in [0,1]:
//   bin 0       : e < 2^-7
//   E=120..126  : 2^(E-119) buckets each (width 2^-8)
//   bin 255     : e >= 1.0
// Monotone in e; max bucket width 2^-7 (bin 0 only).
__device__ __forceinline__ int err_bin(float e) {
    unsigned u = __float_as_uint(e);
    if (u >= 0x3F800000u) return NB - 1;
    if (u < 0x3C000000u) return 0;
    int m = (int)(u >> 23) - 119;                       // 1..7
    return (1 << m) - 1 + (int)((u & 0x7FFFFFu) >> (23 - m));
}

__global__ __launch_bounds__(HIST_NT)
void lovasz_hist_kernel(const float* __restrict__ logits,
                        const int* __restrict__ gt,
                        u64* __restrict__ part) {
    __shared__ u64 h[NBT];              // esum[0:31] | cnt[32:45] | fg[46:59]
    for (int i = threadIdx.x; i < NBT; i += HIST_NT) h[i] = 0ull;
    __syncthreads();

    // exact cover: 512 blocks * 1024 threads * 2 px = 1,048,576
    const int gid = blockIdx.x * HIST_NT + threadIdx.x;
    const int p0 = gid * 2;
    const int b = p0 >> 18;             // p0 / HW_C (2-aligned, same batch)
    const int hw = p0 & (HW_C - 1);
    const float2* base =
        (const float2*)(logits + (size_t)b * C_CLS * HW_C + hw);

    float2 v[C_CLS];
    float mx0 = -3.4e38f, mx1 = -3.4e38f;
#pragma unroll
    for (int c = 0; c < C_CLS; ++c) {
        v[c] = base[(size_t)c * (HW_C / 2)];
        mx0 = fmaxf(mx0, v[c].x);
        mx1 = fmaxf(mx1, v[c].y);
    }
    float s0 = 0.f, s1 = 0.f;
#pragma unroll
    for (int c = 0; c < C_CLS; ++c) {
        v[c].x = __expf(v[c].x - mx0);
        v[c].y = __expf(v[c].y - mx1);
        s0 += v[c].x;
        s1 += v[c].y;
    }
    const float inv0 = 1.0f / s0;
    const float inv1 = 1.0f / s1;

    const int2 lbl2 = *(const int2*)(gt + p0);
    const bool val0 = (lbl2.x != IGNORE_LBL);
    const bool val1 = (lbl2.y != IGNORE_LBL);

#pragma unroll
    for (int c = 0; c < C_CLS; ++c) {
        if (val0) {
            float prob = v[c].x * inv0;
            bool fg = (c == lbl2.x);
            float e = fmaxf(fg ? (1.0f - prob) : prob, 0.0f);
            unsigned eq = __float2uint_rn(e * ESCALE);
            u64 add = (u64)eq | (1ull << 32) | (fg ? (1ull << 46) : 0ull);
            atomicAdd(&h[c * NB + err_bin(e)], add);
        }
        if (val1) {
            float prob = v[c].y * inv1;
            bool fg = (c == lbl2.y);
            float e = fmaxf(fg ? (1.0f - prob) : prob, 0.0f);
            unsigned eq = __float2uint_rn(e * ESCALE);
            u64 add = (u64)eq | (1ull << 32) | (fg ? (1ull << 46) : 0ull);
            atomicAdd(&h[c * NB + err_bin(e)], add);
        }
    }
    __syncthreads();

    const size_t base_out = (size_t)blockIdx.x * NBT;
    for (int i = threadIdx.x; i < NBT; i += HIST_NT) part[base_out + i] = h[i];
}

// Fold 512 partials -> RED_Q per bin. grid = RED_Q * 19 blocks of 256 thr.
// Block 0 also zeroes the final-accumulator words (runs before scan).
__global__ __launch_bounds__(256)
void lovasz_reduce_kernel(const u64* __restrict__ part,
                          u64* __restrict__ red_es,
                          u64* __restrict__ red_cf,
                          unsigned* __restrict__ acc) {
    if (blockIdx.x == 0 && threadIdx.x < 4) acc[threadIdx.x] = 0u;
    const int q = blockIdx.x / C_CLS;            // 0..RED_Q-1
    const int seg = blockIdx.x % C_CLS;
    const int bin = seg * NB + threadIdx.x;      // 0..NBT-1
    const int p0 = q * (HIST_GRID / RED_Q);
    u64 es = 0; unsigned cn = 0, fgc = 0;
#pragma unroll 4
    for (int p = p0; p < p0 + HIST_GRID / RED_Q; ++p) {
        u64 x = part[(size_t)p * NBT + bin];
        es += x & 0xFFFFFFFFull;
        cn += (unsigned)((x >> 32) & 0x3FFFu);
        fgc += (unsigned)(x >> 46);
    }
    red_es[(size_t)q * NBT + bin] = es;
    red_cf[(size_t)q * NBT + bin] = (u64)cn | ((u64)fgc << 32);
}

// One block per class: fold RED_Q, single-chunk descending scan, and the
// last class block writes the final averaged loss (device-scope atomics).
__global__ __launch_bounds__(NB)
void lovasz_scan_kernel(const u64* __restrict__ red_es,
                        const u64* __restrict__ red_cf,
                        float* __restrict__ loss_acc,    // acc[0]
                        int* __restrict__ pres_acc,      // acc[1]
                        unsigned* __restrict__ done_ctr, // acc[2]
                        float* __restrict__ out) {
    const int c = blockIdx.x;
    const int t = threadIdx.x;                   // 0..255
    const int lane = t & 63;
    const int wave = t >> 6;                     // 4 waves

    __shared__ u64 wtot[4];
    __shared__ u64 sh_total;

    // ---- Phase 0: fold the RED_Q reduced partials (descending bin order) ----
    const int db = NB - 1 - t;
    const size_t bo = (size_t)c * NB + db;
    u64 es = 0, nf = 0;                          // nf = cnt | fg<<32
#pragma unroll
    for (int q = 0; q < RED_Q; ++q) {
        es += red_es[(size_t)q * NBT + bo];
        nf += red_cf[(size_t)q * NBT + bo];
    }
    const double mys = (double)es * (1.0 / (double)ESCALE);

    // ---- Phase 1: inclusive scan over the 256 descending bins ----
    u64 incl = nf;
#pragma unroll
    for (int o = 1; o < 64; o <<= 1) {
        u64 u = __shfl_up(incl, o, 64);
        if (lane >= o) incl += u;
    }
    if (lane == 63) wtot[wave] = incl;
    __syncthreads();
    if (t == 0) {
        u64 run = 0;
#pragma unroll
        for (int w = 0; w < 4; ++w) { u64 x = wtot[w]; wtot[w] = run; run += x; }
        sh_total = run;
    }
    __syncthreads();

    const long long G = (long long)(sh_total >> 32);
    const u64 excl = wtot[wave] + (incl - nf);

    double lsum = 0.0;
    {
        long long n_b = (long long)(nf & 0xffffffffull);
        if (n_b > 0 && G > 0) {
            long long f_b = (long long)(nf >> 32);
            long long k0 = (long long)(excl & 0xffffffffull);
            long long F0 = (long long)(excl >> 32);
            long long I0 = G - F0;
            long long U0 = G + k0 - F0;
            long long F1 = F0 + f_b;
            long long I1 = G - F1;
            long long U1 = G + (k0 + n_b) - F1;
            // dJ = I0/U0 - I1/U1 exactly (int64 cross product, <= 2^41)
            double dJ = (double)(I0 * U1 - I1 * U0) / ((double)U0 * (double)U1);
            lsum = (mys / (double)n_b) * dJ;
        }
    }

    // ---- block reduce (double, 4 waves) ----
    __shared__ double dred[4];
#pragma unroll
    for (int o = 32; o > 0; o >>= 1) lsum += __shfl_down(lsum, o, 64);
    if (lane == 0) dred[wave] = lsum;
    __syncthreads();
    if (t == 0) {
        double tot = dred[0] + dred[1] + dred[2] + dred[3];
        if (G > 0) {
            atomicAdd(loss_acc, (float)tot);
            atomicAdd(pres_acc, 1);
        }
        __threadfence();
        unsigned d = atomicAdd(done_ctr, 1u);
        if (d == C_CLS - 1) {                    // last class block
            float lv = atomicAdd(loss_acc, 0.0f);
            int pv = atomicAdd(pres_acc, 0);
            out[0] = lv / fmaxf((float)pv, 1.0f);
        }
    }
}

extern "C" void kernel_launch(void* const* d_in, const int* in_sizes, int n_in,
                              void* d_out, int out_size, void* d_ws, size_t ws_size,
                              hipStream_t stream) {
    const float* logits = (const float*)d_in[0];
    const int* gt = (const int*)d_in[1];
    float* out = (float*)d_out;

    // workspace layout (all fully overwritten each call; no memset needed)
    size_t partBytes = (size_t)HIST_GRID * NBT * sizeof(u64);       // 19.9 MB
    size_t partPad = (partBytes + 255) & ~(size_t)255;
    size_t redBytes = (size_t)RED_Q * NBT * sizeof(u64);            // 311 KB
    size_t redPad = (redBytes + 255) & ~(size_t)255;
    u64* part = (u64*)d_ws;
    u64* red_es = (u64*)((char*)d_ws + partPad);
    u64* red_cf = (u64*)((char*)d_ws + partPad + redPad);
    unsigned* acc = (unsigned*)((char*)d_ws + partPad + 2 * redPad);
    float* loss_acc = (float*)&acc[0];
    int* pres_acc = (int*)&acc[1];
    unsigned* done_ctr = &acc[2];

    lovasz_hist_kernel<<<HIST_GRID, HIST_NT, 0, stream>>>(logits, gt, part);
    lovasz_reduce_kernel<<<RED_Q * C_CLS, 256, 0, stream>>>(part, red_es, red_cf, acc);
    lovasz_scan_kernel<<<C_CLS, NB, 0, stream>>>(red_es, red_cf,
                                                 loss_acc, pres_acc, done_ctr, out);
}